// Round 3
// baseline (165.612 us; speedup 1.0000x reference)
//
#include <hip/hip_runtime.h>
#include <hip/hip_bf16.h>

// Fused causal self-attention, B=2, S=4096, E=1024, D=64 (single head).
// Pipeline: wprep (W->bf16 transposed, Wq pre-scaled by 0.125)
//        -> qkv_proj (bf16 MFMA 16x16x32, writes Q,K row-major bf16; V transposed bf16)
//        -> attn (flash, swapped-QK 32x32x16 MFMA, 8-way KV split combined in LDS).
// Workspace use: 3.5 MB total (Wt 384K + Qb/Kb/Vt 1M each); guarded by tripwire.

typedef short short8 __attribute__((ext_vector_type(8)));
typedef float f32x4 __attribute__((ext_vector_type(4)));
typedef float f32x16 __attribute__((ext_vector_type(16)));
typedef unsigned int uint4e __attribute__((ext_vector_type(4)));
typedef unsigned short ushort4e __attribute__((ext_vector_type(4)));

#define NEGINF (-3.0e38f)

static __device__ __forceinline__ unsigned short f2bf(float f) {
  __hip_bfloat16 h = __float2bfloat16(f);
  return __builtin_bit_cast(unsigned short, h);
}

// ---------------- Kernel 1: W prep (transpose + bf16, fold 0.125 into Wq) ----
__global__ void wprep_kernel(const float* __restrict__ Wq, const float* __restrict__ Wk,
                             const float* __restrict__ Wv, unsigned short* __restrict__ Wt) {
  int bid = blockIdx.x;            // 0..191 : w*64 + n
  int w = bid >> 6, n = bid & 63;
  const float* W = (w == 0) ? Wq : ((w == 1) ? Wk : Wv);
  float sc = (w == 0) ? 0.125f : 1.0f;
  for (int k = threadIdx.x; k < 1024; k += 256)
    Wt[((size_t)(w * 64 + n)) * 1024 + k] = f2bf(W[k * 64 + n] * sc);
}

// ---------------- Kernel 2: QKV projection -----------------------------------
// 512 blocks x 64 threads (1 wave). Wave computes 16 rows x 192 cols, K=1024.
// A-frag (16x16x32): row = lane&15, k = (lane>>4)*8 + j  (x, fp32 -> bf16)
// B-frag:            col = lane&15, k = (lane>>4)*8 + j  (Wt[n][k] contiguous)
// C/D:               col = lane&15, row = (lane>>4)*4 + reg   [m89-verified]
__global__ __launch_bounds__(64) void qkv_proj_kernel(
    const float* __restrict__ x, const unsigned short* __restrict__ Wt,
    unsigned short* __restrict__ Qb, unsigned short* __restrict__ Kb,
    unsigned short* __restrict__ Vt) {
  int wave = blockIdx.x;
  int lane = threadIdx.x;
  int r = lane & 15;
  int hi = lane >> 4;
  int sbase = wave * 16;

  const float* xp = x + (size_t)(sbase + r) * 1024 + hi * 8;

  f32x4 acc[12];
#pragma unroll
  for (int t = 0; t < 12; ++t)
#pragma unroll
    for (int i = 0; i < 4; ++i) acc[t][i] = 0.f;

  for (int k0 = 0; k0 < 1024; k0 += 32) {
    f32x4 a0 = *(const f32x4*)(xp + k0);
    f32x4 a1 = *(const f32x4*)(xp + k0 + 4);
    short8 af;
#pragma unroll
    for (int j = 0; j < 4; ++j) {
      af[j] = (short)f2bf(a0[j]);
      af[4 + j] = (short)f2bf(a1[j]);
    }
#pragma unroll
    for (int t = 0; t < 12; ++t) {
      const unsigned short* wp =
          Wt + ((size_t)((t >> 2) * 64 + (t & 3) * 16 + r)) * 1024 + k0 + hi * 8;
      short8 bf = *(const short8*)wp;
      acc[t] = __builtin_amdgcn_mfma_f32_16x16x32_bf16(af, bf, acc[t], 0, 0, 0);
    }
  }

  int orow = sbase + hi * 4;        // + reg
  int bidx = orow >> 12;
  int so = orow & 4095;
  // Q tiles 0..3 (row-major bf16)
#pragma unroll
  for (int t = 0; t < 4; ++t)
#pragma unroll
    for (int v = 0; v < 4; ++v)
      Qb[(size_t)(orow + v) * 64 + t * 16 + r] = f2bf(acc[t][v]);
  // K tiles 4..7
#pragma unroll
  for (int t = 4; t < 8; ++t)
#pragma unroll
    for (int v = 0; v < 4; ++v)
      Kb[(size_t)(orow + v) * 64 + (t - 4) * 16 + r] = f2bf(acc[t][v]);
  // V tiles 8..11 -> transposed Vt[b][d][s], 4 consecutive s -> 8B store
#pragma unroll
  for (int t = 8; t < 12; ++t) {
    int d = (t - 8) * 16 + r;
    ushort4e pk;
#pragma unroll
    for (int v = 0; v < 4; ++v) pk[v] = f2bf(acc[t][v]);
    *(ushort4e*)(Vt + ((size_t)(bidx * 64 + d)) * 4096 + so) = pk;
  }
}

// ---------------- Kernel 3: flash attention (swapped-QK, 32x32x16) -----------
// 256 blocks x 512 threads (8 waves). Block = one 32-row Q-tile; wave p handles
// KV blocks p, p+8, ... ; 8 partials merged in LDS (no global partials).
// S^T = K.Q^T : C/D col = lane&31 = q-row ; row = kv = (reg&3)+8*(reg>>2)+4*(lane>>5)
__global__ __launch_bounds__(512) void attn_kernel(
    const unsigned short* __restrict__ Qb, const unsigned short* __restrict__ Kb,
    const unsigned short* __restrict__ Vt, float* __restrict__ out) {
  int qglob = blockIdx.x;           // 0..255
  int b = qglob >> 7;
  int q = qglob & 127;
  int lane = threadIdx.x & 63;
  int p = threadIdx.x >> 6;         // wave index = KV part 0..7
  int ql = lane & 31;
  int h = lane >> 5;
  int sbase = q * 32;

  __shared__ float sm[8][32];
  __shared__ float O_lds[32][65];   // stride 65: (ql + d) % 32 banks, conflict-free
  __shared__ float L_lds[32];

  for (int i = threadIdx.x; i < 32 * 65; i += 512) (&O_lds[0][0])[i] = 0.f;
  if (threadIdx.x < 32) L_lds[threadIdx.x] = 0.f;

  // Q^T B-frags: lane holds Q[q=lane&31][dk*16 + h*8 + j] (pre-scaled by 0.125)
  const unsigned short* Qp = Qb + ((size_t)(b * 4096 + sbase + ql)) * 64 + h * 8;
  short8 qf0 = *(const short8*)(Qp);
  short8 qf1 = *(const short8*)(Qp + 16);
  short8 qf2 = *(const short8*)(Qp + 32);
  short8 qf3 = *(const short8*)(Qp + 48);

  f32x16 o0, o1;
#pragma unroll
  for (int i = 0; i < 16; ++i) { o0[i] = 0.f; o1[i] = 0.f; }
  float m = NEGINF, l = 0.f;

  for (int kvb = p; kvb <= q; kvb += 8) {
    int kbase = kvb * 32;
    const unsigned short* Kp = Kb + ((size_t)(b * 4096 + kbase + ql)) * 64 + h * 8;
    short8 kf0 = *(const short8*)(Kp);
    short8 kf1 = *(const short8*)(Kp + 16);
    short8 kf2 = *(const short8*)(Kp + 32);
    short8 kf3 = *(const short8*)(Kp + 48);

    f32x16 st;
#pragma unroll
    for (int i = 0; i < 16; ++i) st[i] = 0.f;
    st = __builtin_amdgcn_mfma_f32_32x32x16_bf16(kf0, qf0, st, 0, 0, 0);
    st = __builtin_amdgcn_mfma_f32_32x32x16_bf16(kf1, qf1, st, 0, 0, 0);
    st = __builtin_amdgcn_mfma_f32_32x32x16_bf16(kf2, qf2, st, 0, 0, 0);
    st = __builtin_amdgcn_mfma_f32_32x32x16_bf16(kf3, qf3, st, 0, 0, 0);

    if (kvb == q) {  // diagonal tile: mask kv_local > q_local
#pragma unroll
      for (int rg = 0; rg < 16; ++rg) {
        int kvl = (rg & 3) + 8 * (rg >> 2) + 4 * h;
        if (kvl > ql) st[rg] = NEGINF;
      }
    }

    float tm = st[0];
#pragma unroll
    for (int rg = 1; rg < 16; ++rg) tm = fmaxf(tm, st[rg]);
    tm = fmaxf(tm, __shfl_xor(tm, 32));
    float nm = fmaxf(m, tm);
    float alpha = __expf(m - nm);
    float ps[16];
    float sum = 0.f;
#pragma unroll
    for (int rg = 0; rg < 16; ++rg) {
      ps[rg] = __expf(st[rg] - nm);
      sum += ps[rg];
    }
    sum += __shfl_xor(sum, 32);
    l = l * alpha + sum;
    m = nm;
#pragma unroll
    for (int i = 0; i < 16; ++i) { o0[i] *= alpha; o1[i] *= alpha; }

    // pack P -> bf16 pairs; pw[t] covers kv pair (8*(t>>1) + 4h + 2*(t&1), +1)
    unsigned int pw[8];
#pragma unroll
    for (int t = 0; t < 8; ++t)
      pw[t] = (unsigned int)f2bf(ps[2 * t]) | ((unsigned int)f2bf(ps[2 * t + 1]) << 16);
    unsigned int sw[8];
#pragma unroll
    for (int t = 0; t < 8; ++t) sw[t] = __shfl_xor(pw[t], 32);

    // B-frag for PV chunk c: lane needs kv = 16c + 8h + {0..7}
    uint4e bw0 = {h ? sw[2] : pw[0], h ? sw[3] : pw[1], h ? pw[2] : sw[0], h ? pw[3] : sw[1]};
    uint4e bw1 = {h ? sw[6] : pw[4], h ? sw[7] : pw[5], h ? pw[6] : sw[4], h ? pw[7] : sw[5]};
    short8 pb0 = __builtin_bit_cast(short8, bw0);
    short8 pb1 = __builtin_bit_cast(short8, bw1);

    // V^T A-frags: lane holds Vt[b][d = 32t + (lane&31)][kbase + 16c + h*8 + j]
    const unsigned short* Vp = Vt + ((size_t)(b * 64 + ql)) * 4096 + kbase + h * 8;
    short8 vf00 = *(const short8*)(Vp);
    short8 vf01 = *(const short8*)(Vp + 16);
    short8 vf10 = *(const short8*)(Vp + (size_t)32 * 4096);
    short8 vf11 = *(const short8*)(Vp + (size_t)32 * 4096 + 16);

    o0 = __builtin_amdgcn_mfma_f32_32x32x16_bf16(vf00, pb0, o0, 0, 0, 0);
    o0 = __builtin_amdgcn_mfma_f32_32x32x16_bf16(vf01, pb1, o0, 0, 0, 0);
    o1 = __builtin_amdgcn_mfma_f32_32x32x16_bf16(vf10, pb0, o1, 0, 0, 0);
    o1 = __builtin_amdgcn_mfma_f32_32x32x16_bf16(vf11, pb1, o1, 0, 0, 0);
  }

  // ---- in-LDS combine of the 8 KV-split partials ----
  if (h == 0) sm[p][ql] = m;
  __syncthreads();  // also covers the O_lds/L_lds zero-init

  float gm = sm[0][ql];
#pragma unroll
  for (int i = 1; i < 8; ++i) gm = fmaxf(gm, sm[i][ql]);
  float alpha = __expf(m - gm);   // 0 for empty waves (m = NEGINF)

  if (h == 0) atomicAdd(&L_lds[ql], alpha * l);
#pragma unroll
  for (int i = 0; i < 16; ++i) {
    int d = (i & 3) + 8 * (i >> 2) + 4 * h;
    atomicAdd(&O_lds[ql][d], alpha * o0[i]);
    atomicAdd(&O_lds[ql][d + 32], alpha * o1[i]);
  }
  __syncthreads();

  // final write: 512 threads x 4 floats = 32 rows x 64 cols
  int row = threadIdx.x >> 4;
  int c4 = (threadIdx.x & 15) * 4;
  float invl = 1.0f / L_lds[row];
  f32x4 v;
#pragma unroll
  for (int j = 0; j < 4; ++j) v[j] = O_lds[row][c4 + j] * invl;
  *(f32x4*)(out + ((size_t)(b * 4096 + sbase + row)) * 64 + c4) = v;
}

// ---------------- launcher ---------------------------------------------------
extern "C" void kernel_launch(void* const* d_in, const int* in_sizes, int n_in,
                              void* d_out, int out_size, void* d_ws, size_t ws_size,
                              hipStream_t stream) {
  const float* x  = (const float*)d_in[0];
  const float* Wq = (const float*)d_in[1];
  const float* Wk = (const float*)d_in[2];
  const float* Wv = (const float*)d_in[3];
  float* out = (float*)d_out;

  // Tripwire: if the harness workspace is smaller than our layout, skip all
  // launches. Output stays poisoned -> clean "incorrect" verdict instead of an
  // OOB-write container crash (disambiguates infra failures from ws overrun).
  if (ws_size < 3538944) return;

  char* ws = (char*)d_ws;
  unsigned short* Wt = (unsigned short*)(ws + 0);          //  393216 B
  unsigned short* Qb = (unsigned short*)(ws + 393216);     // 1048576 B
  unsigned short* Kb = (unsigned short*)(ws + 1441792);    // 1048576 B
  unsigned short* Vt = (unsigned short*)(ws + 2490368);    // 1048576 B
  // total 3538944 B (~3.5 MB)

  wprep_kernel<<<192, 256, 0, stream>>>(Wq, Wk, Wv, Wt);
  qkv_proj_kernel<<<512, 64, 0, stream>>>(x, Wt, Qb, Kb, Vt);
  attn_kernel<<<256, 512, 0, stream>>>(Qb, Kb, Vt, out);
}

// Round 4
// 134.148 us; speedup vs baseline: 1.2345x; 1.2345x over previous
//
#include <hip/hip_runtime.h>
#include <hip/hip_bf16.h>

// Fused causal self-attention, B=2, S=4096, E=1024, D=64 (single head).
// R4: latency-chain attack. qkv_proj: 4-wave K-split + prefetch + LDS combine.
//     attn: KVBLK=64 (8 worst-case iters), K prefetch, exp2 domain, staged
//     LDS combine (no atomics). wprep: coalesced LDS transpose.

typedef short short8 __attribute__((ext_vector_type(8)));
typedef float f32x4 __attribute__((ext_vector_type(4)));
typedef float f32x16 __attribute__((ext_vector_type(16)));
typedef unsigned int uint4e __attribute__((ext_vector_type(4)));
typedef unsigned short ushort4e __attribute__((ext_vector_type(4)));

#define NEGINF (-3.0e38f)
#define SCQ 0.18033688011112042f   // 0.125 * log2(e): S in log2 domain -> exp2

static __device__ __forceinline__ unsigned short f2bf(float f) {
  __hip_bfloat16 h = __float2bfloat16(f);
  return __builtin_bit_cast(unsigned short, h);
}

static __device__ __forceinline__ f32x16 mfma32(short8 a, short8 b, f32x16 c) {
  return __builtin_amdgcn_mfma_f32_32x32x16_bf16(a, b, c, 0, 0, 0);
}

// ---------------- Kernel 1: W prep (coalesced transpose via LDS) -------------
// 24 blocks (3 W x 8 k-chunks of 128) x 256 threads.
__global__ __launch_bounds__(256) void wprep_kernel(
    const float* __restrict__ Wq, const float* __restrict__ Wk,
    const float* __restrict__ Wv, unsigned short* __restrict__ Wt) {
  int w = blockIdx.x >> 3;
  int kc = blockIdx.x & 7;
  int k0 = kc * 128;
  const float* W = (w == 0) ? Wq : ((w == 1) ? Wk : Wv);
  float sc = (w == 0) ? SCQ : 1.0f;

  __shared__ unsigned short lt[128][66];
#pragma unroll
  for (int i = 0; i < 32; ++i) {
    int e = i * 256 + threadIdx.x;      // 0..8191
    int k = e >> 6, n = e & 63;         // coalesced read (n fast)
    lt[k][n] = f2bf(W[(size_t)(k0 + k) * 64 + n] * sc);
  }
  __syncthreads();
#pragma unroll
  for (int i = 0; i < 32; ++i) {
    int e = i * 256 + threadIdx.x;
    int n = e >> 7, k = e & 127;        // coalesced write (k fast)
    Wt[(size_t)(w * 64 + n) * 1024 + k0 + k] = lt[k][n];
  }
}

// ---------------- Kernel 2: QKV projection -----------------------------------
// 512 blocks x 256 threads (4 waves). Block = 16-row strip; wave w = K-quarter
// [w*256,(w+1)*256). Partial acc combined via LDS tree. Prefetched x loads.
// A-frag (16x16x32): row = lane&15, k = (lane>>4)*8 + j
// B-frag:            col = lane&15, k = (lane>>4)*8 + j
// C/D:               col = lane&15, row = (lane>>4)*4 + reg
__global__ __launch_bounds__(256, 2) void qkv_proj_kernel(
    const float* __restrict__ x, const unsigned short* __restrict__ Wt,
    unsigned short* __restrict__ Qb, unsigned short* __restrict__ Kb,
    unsigned short* __restrict__ Vt) {
  int lane = threadIdx.x & 63;
  int w = threadIdx.x >> 6;
  int r = lane & 15;
  int hi = lane >> 4;
  int sbase = blockIdx.x * 16;

  __shared__ alignas(16) float lds_part[4][3072];   // 48 KB

  const float* xp = x + (size_t)(sbase + r) * 1024 + w * 256 + hi * 8;

  f32x4 acc[12];
#pragma unroll
  for (int t = 0; t < 12; ++t)
#pragma unroll
    for (int i = 0; i < 4; ++i) acc[t][i] = 0.f;

  f32x4 a0 = *(const f32x4*)(xp);
  f32x4 a1 = *(const f32x4*)(xp + 4);
#pragma unroll
  for (int k0 = 0; k0 < 256; k0 += 32) {
    short8 af;
#pragma unroll
    for (int j = 0; j < 4; ++j) {
      af[j] = (short)f2bf(a0[j]);
      af[4 + j] = (short)f2bf(a1[j]);
    }
    if (k0 + 32 < 256) {                 // prefetch next x chunk
      a0 = *(const f32x4*)(xp + k0 + 32);
      a1 = *(const f32x4*)(xp + k0 + 36);
    }
    const unsigned short* wb = Wt + (size_t)r * 1024 + w * 256 + k0 + hi * 8;
#pragma unroll
    for (int t = 0; t < 12; ++t) {
      short8 bf = *(const short8*)(wb + (size_t)((t >> 2) * 64 + (t & 3) * 16) * 1024);
      acc[t] = __builtin_amdgcn_mfma_f32_16x16x32_bf16(af, bf, acc[t], 0, 0, 0);
    }
  }

  float* lp = lds_part[w];
#pragma unroll
  for (int t = 0; t < 12; ++t)
#pragma unroll
    for (int v = 0; v < 4; ++v)
      lp[t * 256 + (hi * 4 + v) * 16 + r] = acc[t][v];
  __syncthreads();

  // Q/K tiles (t=0..7): 512 f32x4-tasks, 2 per thread
#pragma unroll
  for (int i = 0; i < 2; ++i) {
    int task = threadIdx.x + i * 256;
    int t = task >> 6;                   // 0..7
    int off = (task & 63) * 4;
    f32x4 s = *(const f32x4*)(&lds_part[0][t * 256 + off]);
    s += *(const f32x4*)(&lds_part[1][t * 256 + off]);
    s += *(const f32x4*)(&lds_part[2][t * 256 + off]);
    s += *(const f32x4*)(&lds_part[3][t * 256 + off]);
    int row = off >> 4, c0 = off & 15;
    ushort4e pk;
#pragma unroll
    for (int j = 0; j < 4; ++j) pk[j] = f2bf(s[j]);
    unsigned short* dst = (t < 4) ? Qb : Kb;
    *(ushort4e*)(dst + (size_t)(sbase + row) * 64 + (t & 3) * 16 + c0) = pk;
  }
  // V tiles (t=8..11) -> transposed Vt[b][d][s]; one (t,col,rowgroup)/thread
  {
    int t = 8 + (threadIdx.x >> 6);
    int col = (threadIdx.x >> 2) & 15;
    int rg = threadIdx.x & 3;
    ushort4e pk;
#pragma unroll
    for (int j = 0; j < 4; ++j) {
      int idx = t * 256 + (rg * 4 + j) * 16 + col;
      float s = lds_part[0][idx] + lds_part[1][idx] + lds_part[2][idx] + lds_part[3][idx];
      pk[j] = f2bf(s);
    }
    int d = (t - 8) * 16 + col;
    int bidx = sbase >> 12, so = sbase & 4095;
    *(ushort4e*)(Vt + ((size_t)(bidx * 64 + d)) * 4096 + so + rg * 4) = pk;
  }
}

// ---------------- Kernel 3: flash attention (swapped-QK, KVBLK=64) -----------
// 256 blocks x 512 threads (8 waves). Block = 32-row Q-tile; wave p handles KV
// pairs p, p+8, ... (pair = 64 kv rows). Worst wave: 8 iterations.
// S^T = K.Q^T : C/D col = lane&31 = q-row ; kv = (reg&3)+8*(reg>>2)+4*(lane>>5)
__global__ __launch_bounds__(512, 2) void attn_kernel(
    const unsigned short* __restrict__ Qb, const unsigned short* __restrict__ Kb,
    const unsigned short* __restrict__ Vt, float* __restrict__ out) {
  int qglob = blockIdx.x;
  int b = qglob >> 7;
  int q = qglob & 127;
  int lane = threadIdx.x & 63;
  int p = threadIdx.x >> 6;
  int ql = lane & 31;
  int h = lane >> 5;
  int sbase = q * 32;

  __shared__ float sm[8][32];
  __shared__ float sl[8][32];
  __shared__ alignas(16) float Op[8][32][68];   // stride 68 -> 16B-aligned rows

  const unsigned short* Qp = Qb + ((size_t)(b * 4096 + sbase + ql)) * 64 + h * 8;
  short8 qf0 = *(const short8*)(Qp);
  short8 qf1 = *(const short8*)(Qp + 16);
  short8 qf2 = *(const short8*)(Qp + 32);
  short8 qf3 = *(const short8*)(Qp + 48);

  f32x16 o0, o1;
#pragma unroll
  for (int i = 0; i < 16; ++i) { o0[i] = 0.f; o1[i] = 0.f; }
  float m = NEGINF, l = 0.f;

  int npairs = (q + 2) >> 1;             // #pairs of 32-blocks (kb0<=q guaranteed)
  const unsigned short* Kbb = Kb + (size_t)b * 4096 * 64;
  const unsigned short* Vbb = Vt + ((size_t)(b * 64 + ql)) * 4096 + h * 8;

  // preload K for first pair (always in-bounds)
  short8 k0a, k0b, k0c, k0d, k1a, k1b, k1c, k1d;
  {
    const unsigned short* Kp = Kbb + (size_t)(p * 64 + ql) * 64 + h * 8;
    k0a = *(const short8*)(Kp);
    k0b = *(const short8*)(Kp + 16);
    k0c = *(const short8*)(Kp + 32);
    k0d = *(const short8*)(Kp + 48);
    k1a = *(const short8*)(Kp + 2048);
    k1b = *(const short8*)(Kp + 2048 + 16);
    k1c = *(const short8*)(Kp + 2048 + 32);
    k1d = *(const short8*)(Kp + 2048 + 48);
  }

  for (int j = p; j < npairs; j += 8) {
    int kbase = j * 64;
    // V loads issued early, used at the bottom (latency hidden by softmax)
    const unsigned short* Vp = Vbb + kbase;
    short8 vf0 = *(const short8*)(Vp);
    short8 vf1 = *(const short8*)(Vp + 16);
    short8 vf2 = *(const short8*)(Vp + 32);
    short8 vf3 = *(const short8*)(Vp + 48);
    short8 vg0 = *(const short8*)(Vp + 32 * 4096);
    short8 vg1 = *(const short8*)(Vp + 32 * 4096 + 16);
    short8 vg2 = *(const short8*)(Vp + 32 * 4096 + 32);
    short8 vg3 = *(const short8*)(Vp + 32 * 4096 + 48);

    f32x16 st0, st1;
#pragma unroll
    for (int i = 0; i < 16; ++i) { st0[i] = 0.f; st1[i] = 0.f; }
    st0 = mfma32(k0a, qf0, st0);
    st0 = mfma32(k0b, qf1, st0);
    st0 = mfma32(k0c, qf2, st0);
    st0 = mfma32(k0d, qf3, st0);
    st1 = mfma32(k1a, qf0, st1);
    st1 = mfma32(k1b, qf1, st1);
    st1 = mfma32(k1c, qf2, st1);
    st1 = mfma32(k1d, qf3, st1);

    // prefetch next pair's K (WAR on kc regs; softmax below hides latency)
    if (j + 8 < npairs) {
      const unsigned short* Kp = Kbb + (size_t)((j + 8) * 64 + ql) * 64 + h * 8;
      k0a = *(const short8*)(Kp);
      k0b = *(const short8*)(Kp + 16);
      k0c = *(const short8*)(Kp + 32);
      k0d = *(const short8*)(Kp + 48);
      k1a = *(const short8*)(Kp + 2048);
      k1b = *(const short8*)(Kp + 2048 + 16);
      k1c = *(const short8*)(Kp + 2048 + 32);
      k1d = *(const short8*)(Kp + 2048 + 48);
    }

    if (2 * j == q) {                    // diagonal in first half (even q)
#pragma unroll
      for (int rg = 0; rg < 16; ++rg) {
        int kvl = (rg & 3) + 8 * (rg >> 2) + 4 * h;
        if (kvl > ql) st0[rg] = NEGINF;
        st1[rg] = NEGINF;
      }
    } else if (2 * j + 1 == q) {         // diagonal in second half (odd q)
#pragma unroll
      for (int rg = 0; rg < 16; ++rg) {
        int kvl = (rg & 3) + 8 * (rg >> 2) + 4 * h;
        if (kvl > ql) st1[rg] = NEGINF;
      }
    }

    // ---- online softmax over 32 values (log2 domain) ----
    float mx[16];
#pragma unroll
    for (int i = 0; i < 16; ++i) mx[i] = fmaxf(st0[i], st1[i]);
#pragma unroll
    for (int s = 8; s >= 1; s >>= 1)
#pragma unroll
      for (int i = 0; i < s; ++i) mx[i] = fmaxf(mx[i], mx[i + s]);
    float tm = fmaxf(mx[0], __shfl_xor(mx[0], 32));
    float nm = fmaxf(m, tm);
    float alpha = exp2f(m - nm);
#pragma unroll
    for (int i = 0; i < 16; ++i) {       // exp in place (saves 32 VGPR)
      st0[i] = exp2f(st0[i] - nm);
      st1[i] = exp2f(st1[i] - nm);
    }
    float sv[16];
#pragma unroll
    for (int i = 0; i < 16; ++i) sv[i] = st0[i] + st1[i];
#pragma unroll
    for (int s = 8; s >= 1; s >>= 1)
#pragma unroll
      for (int i = 0; i < s; ++i) sv[i] += sv[i + s];
    float sum = sv[0] + __shfl_xor(sv[0], 32);
    l = l * alpha + sum;
    m = nm;
#pragma unroll
    for (int i = 0; i < 16; ++i) { o0[i] *= alpha; o1[i] *= alpha; }

    // ---- pack P -> bf16 B-frags (per half, then cross-half select) ----
    unsigned int pw0[8], pw1[8], sw0[8], sw1[8];
#pragma unroll
    for (int t = 0; t < 8; ++t) {
      pw0[t] = (unsigned int)f2bf(st0[2 * t]) | ((unsigned int)f2bf(st0[2 * t + 1]) << 16);
      pw1[t] = (unsigned int)f2bf(st1[2 * t]) | ((unsigned int)f2bf(st1[2 * t + 1]) << 16);
    }
#pragma unroll
    for (int t = 0; t < 8; ++t) {
      sw0[t] = __shfl_xor(pw0[t], 32);
      sw1[t] = __shfl_xor(pw1[t], 32);
    }
    uint4e bw0 = {h ? sw0[2] : pw0[0], h ? sw0[3] : pw0[1], h ? pw0[2] : sw0[0], h ? pw0[3] : sw0[1]};
    uint4e bw1 = {h ? sw0[6] : pw0[4], h ? sw0[7] : pw0[5], h ? pw0[6] : sw0[4], h ? pw0[7] : sw0[5]};
    uint4e bw2 = {h ? sw1[2] : pw1[0], h ? sw1[3] : pw1[1], h ? pw1[2] : sw1[0], h ? pw1[3] : sw1[1]};
    uint4e bw3 = {h ? sw1[6] : pw1[4], h ? sw1[7] : pw1[5], h ? pw1[6] : sw1[4], h ? pw1[7] : sw1[5]};
    short8 pb0 = __builtin_bit_cast(short8, bw0);
    short8 pb1 = __builtin_bit_cast(short8, bw1);
    short8 pb2 = __builtin_bit_cast(short8, bw2);
    short8 pb3 = __builtin_bit_cast(short8, bw3);

    o0 = mfma32(vf0, pb0, o0);
    o0 = mfma32(vf1, pb1, o0);
    o0 = mfma32(vf2, pb2, o0);
    o0 = mfma32(vf3, pb3, o0);
    o1 = mfma32(vg0, pb0, o1);
    o1 = mfma32(vg1, pb1, o1);
    o1 = mfma32(vg2, pb2, o1);
    o1 = mfma32(vg3, pb3, o1);
  }

  // ---- staged LDS combine of 8 KV-split partials ----
  if (h == 0) sm[p][ql] = m;
  __syncthreads();
  float gm = sm[0][ql];
#pragma unroll
  for (int i = 1; i < 8; ++i) gm = fmaxf(gm, sm[i][ql]);
  float alpha = exp2f(m - gm);           // 0 for empty waves
  if (h == 0) sl[p][ql] = alpha * l;
  float* Ob = &Op[p][ql][0];
#pragma unroll
  for (int u = 0; u < 4; ++u) {
    f32x4 w0 = {alpha * o0[4 * u], alpha * o0[4 * u + 1], alpha * o0[4 * u + 2], alpha * o0[4 * u + 3]};
    *(f32x4*)(Ob + u * 8 + h * 4) = w0;
    f32x4 w1 = {alpha * o1[4 * u], alpha * o1[4 * u + 1], alpha * o1[4 * u + 2], alpha * o1[4 * u + 3]};
    *(f32x4*)(Ob + 32 + u * 8 + h * 4) = w1;
  }
  __syncthreads();

  int row = threadIdx.x >> 4;
  int c4 = (threadIdx.x & 15) * 4;
  f32x4 accv = *(const f32x4*)(&Op[0][row][c4]);
#pragma unroll
  for (int pp = 1; pp < 8; ++pp) accv += *(const f32x4*)(&Op[pp][row][c4]);
  float lsum = sl[0][row];
#pragma unroll
  for (int pp = 1; pp < 8; ++pp) lsum += sl[pp][row];
  float invl = 1.0f / lsum;
  f32x4 res;
#pragma unroll
  for (int j = 0; j < 4; ++j) res[j] = accv[j] * invl;
  *(f32x4*)(out + ((size_t)(b * 4096 + sbase + row)) * 64 + c4) = res;
}

// ---------------- launcher ---------------------------------------------------
extern "C" void kernel_launch(void* const* d_in, const int* in_sizes, int n_in,
                              void* d_out, int out_size, void* d_ws, size_t ws_size,
                              hipStream_t stream) {
  const float* x  = (const float*)d_in[0];
  const float* Wq = (const float*)d_in[1];
  const float* Wk = (const float*)d_in[2];
  const float* Wv = (const float*)d_in[3];
  float* out = (float*)d_out;

  if (ws_size < 3538944) return;  // tripwire (see R3 note)

  char* ws = (char*)d_ws;
  unsigned short* Wt = (unsigned short*)(ws + 0);          //  393216 B
  unsigned short* Qb = (unsigned short*)(ws + 393216);     // 1048576 B
  unsigned short* Kb = (unsigned short*)(ws + 1441792);    // 1048576 B
  unsigned short* Vt = (unsigned short*)(ws + 2490368);    // 1048576 B

  wprep_kernel<<<24, 256, 0, stream>>>(Wq, Wk, Wv, Wt);
  qkv_proj_kernel<<<512, 256, 0, stream>>>(x, Wt, Qb, Kb, Vt);
  attn_kernel<<<256, 512, 0, stream>>>(Qb, Kb, Vt, out);
}

// Round 6
// 128.098 us; speedup vs baseline: 1.2929x; 1.0472x over previous
//
#include <hip/hip_runtime.h>
#include <hip/hip_bf16.h>

// Fused causal self-attention, B=2, S=4096, E=1024, D=64 (single head).
// R6: R5's structure (1024 blocks x 4 waves, 16-way KV split, heavy-first,
//     global partials + combine, setprio) with R4's verified shfl_xor
//     exchanges restored (R5's inline-asm permlane32_swap was the prime
//     suspect for the correctness failure; reverted pending isolated retest).

typedef short short8 __attribute__((ext_vector_type(8)));
typedef float f32x4 __attribute__((ext_vector_type(4)));
typedef float f32x16 __attribute__((ext_vector_type(16)));
typedef unsigned int uint4e __attribute__((ext_vector_type(4)));
typedef unsigned short ushort4e __attribute__((ext_vector_type(4)));

#define NEGINF (-3.0e38f)
#define SCQ 0.18033688011112042f   // 0.125 * log2(e): S in log2 domain -> exp2

static __device__ __forceinline__ unsigned short f2bf(float f) {
  __hip_bfloat16 h = __float2bfloat16(f);
  return __builtin_bit_cast(unsigned short, h);
}
static __device__ __forceinline__ f32x16 mfma32(short8 a, short8 b, f32x16 c) {
  return __builtin_amdgcn_mfma_f32_32x32x16_bf16(a, b, c, 0, 0, 0);
}

// ---------------- Kernel 1: W prep (coalesced transpose via LDS) -------------
__global__ __launch_bounds__(256) void wprep_kernel(
    const float* __restrict__ Wq, const float* __restrict__ Wk,
    const float* __restrict__ Wv, unsigned short* __restrict__ Wt) {
  int w = blockIdx.x >> 3;
  int kc = blockIdx.x & 7;
  int k0 = kc * 128;
  const float* W = (w == 0) ? Wq : ((w == 1) ? Wk : Wv);
  float sc = (w == 0) ? SCQ : 1.0f;

  __shared__ unsigned short lt[128][66];
#pragma unroll
  for (int i = 0; i < 32; ++i) {
    int e = i * 256 + threadIdx.x;
    int k = e >> 6, n = e & 63;
    lt[k][n] = f2bf(W[(size_t)(k0 + k) * 64 + n] * sc);
  }
  __syncthreads();
#pragma unroll
  for (int i = 0; i < 32; ++i) {
    int e = i * 256 + threadIdx.x;
    int n = e >> 7, k = e & 127;
    Wt[(size_t)(w * 64 + n) * 1024 + k0 + k] = lt[k][n];
  }
}

// ---------------- Kernel 2: QKV projection (frozen from R4) ------------------
__global__ __launch_bounds__(256, 2) void qkv_proj_kernel(
    const float* __restrict__ x, const unsigned short* __restrict__ Wt,
    unsigned short* __restrict__ Qb, unsigned short* __restrict__ Kb,
    unsigned short* __restrict__ Vt) {
  int lane = threadIdx.x & 63;
  int w = threadIdx.x >> 6;
  int r = lane & 15;
  int hi = lane >> 4;
  int sbase = blockIdx.x * 16;

  __shared__ alignas(16) float lds_part[4][3072];

  const float* xp = x + (size_t)(sbase + r) * 1024 + w * 256 + hi * 8;

  f32x4 acc[12];
#pragma unroll
  for (int t = 0; t < 12; ++t)
#pragma unroll
    for (int i = 0; i < 4; ++i) acc[t][i] = 0.f;

  f32x4 a0 = *(const f32x4*)(xp);
  f32x4 a1 = *(const f32x4*)(xp + 4);
#pragma unroll
  for (int k0 = 0; k0 < 256; k0 += 32) {
    short8 af;
#pragma unroll
    for (int j = 0; j < 4; ++j) {
      af[j] = (short)f2bf(a0[j]);
      af[4 + j] = (short)f2bf(a1[j]);
    }
    if (k0 + 32 < 256) {
      a0 = *(const f32x4*)(xp + k0 + 32);
      a1 = *(const f32x4*)(xp + k0 + 36);
    }
    const unsigned short* wb = Wt + (size_t)r * 1024 + w * 256 + k0 + hi * 8;
#pragma unroll
    for (int t = 0; t < 12; ++t) {
      short8 bf = *(const short8*)(wb + (size_t)((t >> 2) * 64 + (t & 3) * 16) * 1024);
      acc[t] = __builtin_amdgcn_mfma_f32_16x16x32_bf16(af, bf, acc[t], 0, 0, 0);
    }
  }

  float* lp = lds_part[w];
#pragma unroll
  for (int t = 0; t < 12; ++t)
#pragma unroll
    for (int v = 0; v < 4; ++v)
      lp[t * 256 + (hi * 4 + v) * 16 + r] = acc[t][v];
  __syncthreads();

#pragma unroll
  for (int i = 0; i < 2; ++i) {
    int task = threadIdx.x + i * 256;
    int t = task >> 6;
    int off = (task & 63) * 4;
    f32x4 s = *(const f32x4*)(&lds_part[0][t * 256 + off]);
    s += *(const f32x4*)(&lds_part[1][t * 256 + off]);
    s += *(const f32x4*)(&lds_part[2][t * 256 + off]);
    s += *(const f32x4*)(&lds_part[3][t * 256 + off]);
    int row = off >> 4, c0 = off & 15;
    ushort4e pk;
#pragma unroll
    for (int j = 0; j < 4; ++j) pk[j] = f2bf(s[j]);
    unsigned short* dst = (t < 4) ? Qb : Kb;
    *(ushort4e*)(dst + (size_t)(sbase + row) * 64 + (t & 3) * 16 + c0) = pk;
  }
  {
    int t = 8 + (threadIdx.x >> 6);
    int col = (threadIdx.x >> 2) & 15;
    int rg = threadIdx.x & 3;
    ushort4e pk;
#pragma unroll
    for (int j = 0; j < 4; ++j) {
      int idx = t * 256 + (rg * 4 + j) * 16 + col;
      float s = lds_part[0][idx] + lds_part[1][idx] + lds_part[2][idx] + lds_part[3][idx];
      pk[j] = f2bf(s);
    }
    int d = (t - 8) * 16 + col;
    int bidx = sbase >> 12, so = sbase & 4095;
    *(ushort4e*)(Vt + ((size_t)(bidx * 64 + d)) * 4096 + so + rg * 4) = pk;
  }
}

// ---------------- Kernel 3: flash attention ----------------------------------
// 1024 blocks x 256 threads (4 waves). bid -> (qidx heavy-first, b, hh).
// Wave part g = hh*4 + p handles KV pairs g, g+16, ... (pair = 64 rows).
// Worst wave: 4 iterations. Per-block LDS combine -> global partial (O,m,l).
// S^T = K.Q^T : C/D col = lane&31 = q-row ; kv = (reg&3)+8*(reg>>2)+4*(lane>>5)
__global__ __launch_bounds__(256, 2) void attn_kernel(
    const unsigned short* __restrict__ Qb, const unsigned short* __restrict__ Kb,
    const unsigned short* __restrict__ Vt, float* __restrict__ Opart,
    float* __restrict__ Mpart, float* __restrict__ Lpart) {
  int bid = blockIdx.x;             // 0..1023
  int q = 127 - (bid >> 3);         // heavy q first
  int b = (bid >> 2) & 1;
  int hh = bid & 3;
  int lane = threadIdx.x & 63;
  int p = threadIdx.x >> 6;         // 0..3
  int g = hh * 4 + p;               // KV part 0..15
  int ql = lane & 31;
  int h = lane >> 5;
  int sbase = q * 32;

  __shared__ float sm[4][32];
  __shared__ float sl[4][32];
  __shared__ alignas(16) float Op[4][32][68];

  const unsigned short* Qp = Qb + ((size_t)(b * 4096 + sbase + ql)) * 64 + h * 8;
  short8 qf0 = *(const short8*)(Qp);
  short8 qf1 = *(const short8*)(Qp + 16);
  short8 qf2 = *(const short8*)(Qp + 32);
  short8 qf3 = *(const short8*)(Qp + 48);

  f32x16 o0, o1;
#pragma unroll
  for (int i = 0; i < 16; ++i) { o0[i] = 0.f; o1[i] = 0.f; }
  float m = NEGINF, l = 0.f;

  int npairs = (q + 2) >> 1;
  const unsigned short* Kbb = Kb + (size_t)b * 4096 * 64;
  const unsigned short* Vbb = Vt + ((size_t)(b * 64 + ql)) * 4096 + h * 8;

  short8 k0a, k0b, k0c, k0d, k1a, k1b, k1c, k1d;
  {
    const unsigned short* Kp = Kbb + (size_t)(g * 64 + ql) * 64 + h * 8;
    k0a = *(const short8*)(Kp);
    k0b = *(const short8*)(Kp + 16);
    k0c = *(const short8*)(Kp + 32);
    k0d = *(const short8*)(Kp + 48);
    k1a = *(const short8*)(Kp + 2048);
    k1b = *(const short8*)(Kp + 2048 + 16);
    k1c = *(const short8*)(Kp + 2048 + 32);
    k1d = *(const short8*)(Kp + 2048 + 48);
  }

  for (int j = g; j < npairs; j += 16) {
    int kbase = j * 64;
    const unsigned short* Vp = Vbb + kbase;
    short8 vf0 = *(const short8*)(Vp);
    short8 vf1 = *(const short8*)(Vp + 16);
    short8 vf2 = *(const short8*)(Vp + 32);
    short8 vf3 = *(const short8*)(Vp + 48);
    short8 vg0 = *(const short8*)(Vp + 32 * 4096);
    short8 vg1 = *(const short8*)(Vp + 32 * 4096 + 16);
    short8 vg2 = *(const short8*)(Vp + 32 * 4096 + 32);
    short8 vg3 = *(const short8*)(Vp + 32 * 4096 + 48);

    f32x16 st0, st1;
#pragma unroll
    for (int i = 0; i < 16; ++i) { st0[i] = 0.f; st1[i] = 0.f; }
    __builtin_amdgcn_s_setprio(1);
    st0 = mfma32(k0a, qf0, st0);
    st0 = mfma32(k0b, qf1, st0);
    st0 = mfma32(k0c, qf2, st0);
    st0 = mfma32(k0d, qf3, st0);
    st1 = mfma32(k1a, qf0, st1);
    st1 = mfma32(k1b, qf1, st1);
    st1 = mfma32(k1c, qf2, st1);
    st1 = mfma32(k1d, qf3, st1);
    __builtin_amdgcn_s_setprio(0);

    if (j + 16 < npairs) {          // prefetch next pair's K
      const unsigned short* Kp = Kbb + (size_t)((j + 16) * 64 + ql) * 64 + h * 8;
      k0a = *(const short8*)(Kp);
      k0b = *(const short8*)(Kp + 16);
      k0c = *(const short8*)(Kp + 32);
      k0d = *(const short8*)(Kp + 48);
      k1a = *(const short8*)(Kp + 2048);
      k1b = *(const short8*)(Kp + 2048 + 16);
      k1c = *(const short8*)(Kp + 2048 + 32);
      k1d = *(const short8*)(Kp + 2048 + 48);
    }

    if (2 * j == q) {
#pragma unroll
      for (int rg = 0; rg < 16; ++rg) {
        int kvl = (rg & 3) + 8 * (rg >> 2) + 4 * h;
        if (kvl > ql) st0[rg] = NEGINF;
        st1[rg] = NEGINF;
      }
    } else if (2 * j + 1 == q) {
#pragma unroll
      for (int rg = 0; rg < 16; ++rg) {
        int kvl = (rg & 3) + 8 * (rg >> 2) + 4 * h;
        if (kvl > ql) st1[rg] = NEGINF;
      }
    }

    // ---- online softmax over 32 values (log2 domain) ----
    float mx[16];
#pragma unroll
    for (int i = 0; i < 16; ++i) mx[i] = fmaxf(st0[i], st1[i]);
#pragma unroll
    for (int s = 8; s >= 1; s >>= 1)
#pragma unroll
      for (int i = 0; i < s; ++i) mx[i] = fmaxf(mx[i], mx[i + s]);
    float tm = fmaxf(mx[0], __shfl_xor(mx[0], 32));
    float nm = fmaxf(m, tm);
    float alpha = exp2f(m - nm);
#pragma unroll
    for (int i = 0; i < 16; ++i) {
      st0[i] = exp2f(st0[i] - nm);
      st1[i] = exp2f(st1[i] - nm);
    }
    float sv[16];
#pragma unroll
    for (int i = 0; i < 16; ++i) sv[i] = st0[i] + st1[i];
#pragma unroll
    for (int s = 8; s >= 1; s >>= 1)
#pragma unroll
      for (int i = 0; i < s; ++i) sv[i] += sv[i + s];
    float sum = sv[0] + __shfl_xor(sv[0], 32);
    l = l * alpha + sum;
    m = nm;
#pragma unroll
    for (int i = 0; i < 16; ++i) { o0[i] *= alpha; o1[i] *= alpha; }

    // ---- pack P -> bf16 B-frags (R4-verified shfl_xor exchange) ----
    unsigned int pw0[8], pw1[8], sw0[8], sw1[8];
#pragma unroll
    for (int t = 0; t < 8; ++t) {
      pw0[t] = (unsigned int)f2bf(st0[2 * t]) | ((unsigned int)f2bf(st0[2 * t + 1]) << 16);
      pw1[t] = (unsigned int)f2bf(st1[2 * t]) | ((unsigned int)f2bf(st1[2 * t + 1]) << 16);
    }
#pragma unroll
    for (int t = 0; t < 8; ++t) {
      sw0[t] = __shfl_xor(pw0[t], 32);
      sw1[t] = __shfl_xor(pw1[t], 32);
    }
    uint4e bw0 = {h ? sw0[2] : pw0[0], h ? sw0[3] : pw0[1], h ? pw0[2] : sw0[0], h ? pw0[3] : sw0[1]};
    uint4e bw1 = {h ? sw0[6] : pw0[4], h ? sw0[7] : pw0[5], h ? pw0[6] : sw0[4], h ? pw0[7] : sw0[5]};
    uint4e bw2 = {h ? sw1[2] : pw1[0], h ? sw1[3] : pw1[1], h ? pw1[2] : sw1[0], h ? pw1[3] : sw1[1]};
    uint4e bw3 = {h ? sw1[6] : pw1[4], h ? sw1[7] : pw1[5], h ? pw1[6] : sw1[4], h ? pw1[7] : sw1[5]};
    short8 pb0 = __builtin_bit_cast(short8, bw0);
    short8 pb1 = __builtin_bit_cast(short8, bw1);
    short8 pb2 = __builtin_bit_cast(short8, bw2);
    short8 pb3 = __builtin_bit_cast(short8, bw3);

    __builtin_amdgcn_s_setprio(1);
    o0 = mfma32(vf0, pb0, o0);
    o0 = mfma32(vf1, pb1, o0);
    o0 = mfma32(vf2, pb2, o0);
    o0 = mfma32(vf3, pb3, o0);
    o1 = mfma32(vg0, pb0, o1);
    o1 = mfma32(vg1, pb1, o1);
    o1 = mfma32(vg2, pb2, o1);
    o1 = mfma32(vg3, pb3, o1);
    __builtin_amdgcn_s_setprio(0);
  }

  // ---- LDS combine of this block's 4 waves -> global partial ----
  if (h == 0) sm[p][ql] = m;
  __syncthreads();
  float gm = sm[0][ql];
#pragma unroll
  for (int i = 1; i < 4; ++i) gm = fmaxf(gm, sm[i][ql]);
  float alpha = exp2f(m - gm);      // 0 for empty waves; 1 if all empty (l=0)
  if (h == 0) sl[p][ql] = alpha * l;
  float* Ob = &Op[p][ql][0];
#pragma unroll
  for (int u = 0; u < 4; ++u) {
    f32x4 w0 = {alpha * o0[4 * u], alpha * o0[4 * u + 1], alpha * o0[4 * u + 2], alpha * o0[4 * u + 3]};
    *(f32x4*)(Ob + u * 8 + h * 4) = w0;
    f32x4 w1 = {alpha * o1[4 * u], alpha * o1[4 * u + 1], alpha * o1[4 * u + 2], alpha * o1[4 * u + 3]};
    *(f32x4*)(Ob + 32 + u * 8 + h * 4) = w1;
  }
  __syncthreads();

  // write partial: O (32x64 f32), m (gm), l (sum of rescaled l)
  float* Od = Opart + (size_t)bid * 2048;
#pragma unroll
  for (int i = 0; i < 2; ++i) {
    int task = threadIdx.x + i * 256;
    int row = task >> 4;
    int c4 = (task & 15) * 4;
    f32x4 accv = *(const f32x4*)(&Op[0][row][c4]);
#pragma unroll
    for (int pp = 1; pp < 4; ++pp) accv += *(const f32x4*)(&Op[pp][row][c4]);
    *(f32x4*)(Od + row * 64 + c4) = accv;
  }
  if (threadIdx.x < 32) {
    int row = threadIdx.x;
    float gmv = fmaxf(fmaxf(sm[0][row], sm[1][row]), fmaxf(sm[2][row], sm[3][row]));
    Mpart[(size_t)bid * 32 + row] = gmv;
    Lpart[(size_t)bid * 32 + row] = sl[0][row] + sl[1][row] + sl[2][row] + sl[3][row];
  }
}

// ---------------- Kernel 4: combine 4 partials per q-tile --------------------
__global__ __launch_bounds__(256) void combine_kernel(
    const float* __restrict__ Opart, const float* __restrict__ Mpart,
    const float* __restrict__ Lpart, float* __restrict__ out) {
  int gid = blockIdx.x * 256 + threadIdx.x;   // 0..131071
  int c4 = (gid & 15) * 4;
  int row = gid >> 4;                         // b*4096 + s
  int r = row & 31;
  int qg = row >> 5;                          // b*128 + q
  int b = qg >> 7, q = qg & 127;
  int base = (127 - q) * 8 + b * 4;           // 4 partial blocks

  float mm[4];
  float gm = NEGINF;
#pragma unroll
  for (int i = 0; i < 4; ++i) {
    mm[i] = Mpart[(size_t)(base + i) * 32 + r];
    gm = fmaxf(gm, mm[i]);
  }
  float L = 0.f;
  f32x4 o = {0.f, 0.f, 0.f, 0.f};
#pragma unroll
  for (int i = 0; i < 4; ++i) {
    float e = exp2f(mm[i] - gm);
    L += e * Lpart[(size_t)(base + i) * 32 + r];
    f32x4 ov = *(const f32x4*)(Opart + (size_t)(base + i) * 2048 + r * 64 + c4);
    o += e * ov;
  }
  float invl = 1.0f / L;
  f32x4 res = {o[0] * invl, o[1] * invl, o[2] * invl, o[3] * invl};
  *(f32x4*)(out + (size_t)row * 64 + c4) = res;
}

// ---------------- launcher ---------------------------------------------------
extern "C" void kernel_launch(void* const* d_in, const int* in_sizes, int n_in,
                              void* d_out, int out_size, void* d_ws, size_t ws_size,
                              hipStream_t stream) {
  const float* x  = (const float*)d_in[0];
  const float* Wq = (const float*)d_in[1];
  const float* Wk = (const float*)d_in[2];
  const float* Wv = (const float*)d_in[3];
  float* out = (float*)d_out;

  if (ws_size < 12189696) return;  // tripwire (ws is ~268 MB per R4 fill size)

  char* ws = (char*)d_ws;
  unsigned short* Wt = (unsigned short*)(ws + 0);          //   393216 B
  unsigned short* Qb = (unsigned short*)(ws + 393216);     //  1048576 B
  unsigned short* Kb = (unsigned short*)(ws + 1441792);    //  1048576 B
  unsigned short* Vt = (unsigned short*)(ws + 2490368);    //  1048576 B
  float* Opart = (float*)(ws + 3538944);                   //  8388608 B
  float* Mpart = (float*)(ws + 11927552);                  //   131072 B
  float* Lpart = (float*)(ws + 12058624);                  //   131072 B

  wprep_kernel<<<24, 256, 0, stream>>>(Wq, Wk, Wv, Wt);
  qkv_proj_kernel<<<512, 256, 0, stream>>>(x, Wt, Qb, Kb, Vt);
  attn_kernel<<<1024, 256, 0, stream>>>(Qb, Kb, Vt, Opart, Mpart, Lpart);
  combine_kernel<<<512, 256, 0, stream>>>(Opart, Mpart, Lpart, out);
}

// Round 7
// 125.273 us; speedup vs baseline: 1.3220x; 1.0225x over previous
//
#include <hip/hip_runtime.h>
#include <hip/hip_bf16.h>

// Fused causal self-attention, B=2, S=4096, E=1024, D=64 (single head).
// R7: qkv_proj rebuilt as LDS-tiled GEMM (256 blocks x 8 waves, 32-row tile,
//     K=32 chunks double-buffered in LDS, padded 40-short rows, b128 frags,
//     no cross-wave combine). attn/wprep/combine FROZEN from R6 (attribution).

typedef short short8 __attribute__((ext_vector_type(8)));
typedef float f32x2 __attribute__((ext_vector_type(2)));
typedef float f32x4 __attribute__((ext_vector_type(4)));
typedef float f32x16 __attribute__((ext_vector_type(16)));
typedef unsigned int uint4e __attribute__((ext_vector_type(4)));
typedef unsigned short ushort4e __attribute__((ext_vector_type(4)));

#define NEGINF (-3.0e38f)
#define SCQ 0.18033688011112042f   // 0.125 * log2(e): S in log2 domain -> exp2

static __device__ __forceinline__ unsigned short f2bf(float f) {
  __hip_bfloat16 h = __float2bfloat16(f);
  return __builtin_bit_cast(unsigned short, h);
}
static __device__ __forceinline__ f32x16 mfma32(short8 a, short8 b, f32x16 c) {
  return __builtin_amdgcn_mfma_f32_32x32x16_bf16(a, b, c, 0, 0, 0);
}

// ---------------- Kernel 1: W prep (coalesced transpose via LDS) -------------
__global__ __launch_bounds__(256) void wprep_kernel(
    const float* __restrict__ Wq, const float* __restrict__ Wk,
    const float* __restrict__ Wv, unsigned short* __restrict__ Wt) {
  int w = blockIdx.x >> 3;
  int kc = blockIdx.x & 7;
  int k0 = kc * 128;
  const float* W = (w == 0) ? Wq : ((w == 1) ? Wk : Wv);
  float sc = (w == 0) ? SCQ : 1.0f;

  __shared__ unsigned short lt[128][66];
#pragma unroll
  for (int i = 0; i < 32; ++i) {
    int e = i * 256 + threadIdx.x;
    int k = e >> 6, n = e & 63;
    lt[k][n] = f2bf(W[(size_t)(k0 + k) * 64 + n] * sc);
  }
  __syncthreads();
#pragma unroll
  for (int i = 0; i < 32; ++i) {
    int e = i * 256 + threadIdx.x;
    int n = e >> 7, k = e & 127;
    Wt[(size_t)(w * 64 + n) * 1024 + k0 + k] = lt[k][n];
  }
}

// ---------------- Kernel 2: QKV projection (R7 LDS-tiled) --------------------
// 256 blocks x 512 threads (8 waves). Block = 32 rows x 192 cols, K=1024 in
// 32-wide chunks double-buffered in LDS. Wave (rt=w>>2, cg=w&3) owns
// 16 rows x 48 cols (3 tiles), full K -> no partial combine.
// A-frag (16x16x32): row = lane&15, k = (lane>>4)*8 + j
// B-frag:            col = lane&15, k = (lane>>4)*8 + j
// C/D:               col = lane&15, row = (lane>>4)*4 + reg
__global__ __launch_bounds__(512) void qkv_proj_kernel(
    const float* __restrict__ x, const unsigned short* __restrict__ Wt,
    unsigned short* __restrict__ Qb, unsigned short* __restrict__ Kb,
    unsigned short* __restrict__ Vt) {
  int tid = threadIdx.x;
  int lane = tid & 63;
  int wv = tid >> 6;          // 0..7
  int rt = wv >> 2;           // row half (16 rows)
  int cg = wv & 3;            // col group (48 cols = 3 tiles)
  int r = lane & 15;
  int hi = lane >> 4;
  int sbase = blockIdx.x * 32;

  // padded rows: 40 shorts = 80 B -> 16B-aligned b128 frags, balanced banks
  __shared__ alignas(16) unsigned short xs[2][32][40];    //  5.1 KB
  __shared__ alignas(16) unsigned short wsl[2][192][40];  // 30.7 KB

  // stage-task constants
  int xrow = tid >> 4;              // 0..31
  int xcol = (tid & 15) * 2;        // 0..30
  int p1 = tid;                     // Wt piece (row = p>>2, off = (p&3)*8)
  int p2 = tid + 512;               // second piece for tid < 256
  const float* xg = x + (size_t)(sbase + xrow) * 1024 + xcol;

  f32x4 acc[3];
#pragma unroll
  for (int t = 0; t < 3; ++t)
#pragma unroll
    for (int i = 0; i < 4; ++i) acc[t][i] = 0.f;

  // ---- stage chunk 0 ----
  {
    f32x2 xv = *(const f32x2*)(xg);
    unsigned int pk = (unsigned int)f2bf(xv[0]) | ((unsigned int)f2bf(xv[1]) << 16);
    *(unsigned int*)&xs[0][xrow][xcol] = pk;
    short8 wva = *(const short8*)(Wt + (size_t)(p1 >> 2) * 1024 + (p1 & 3) * 8);
    *(short8*)&wsl[0][p1 >> 2][(p1 & 3) * 8] = wva;
    if (tid < 256) {
      short8 wvb = *(const short8*)(Wt + (size_t)(p2 >> 2) * 1024 + (p2 & 3) * 8);
      *(short8*)&wsl[0][p2 >> 2][(p2 & 3) * 8] = wvb;
    }
  }
  __syncthreads();

  for (int c = 0; c < 32; ++c) {
    int cur = c & 1;
    bool has_next = (c + 1) < 32;
    // issue next-chunk global loads early
    f32x2 xv;
    short8 wva, wvb;
    if (has_next) {
      int k0 = (c + 1) * 32;
      xv = *(const f32x2*)(xg + k0);
      wva = *(const short8*)(Wt + (size_t)(p1 >> 2) * 1024 + k0 + (p1 & 3) * 8);
      if (tid < 256)
        wvb = *(const short8*)(Wt + (size_t)(p2 >> 2) * 1024 + k0 + (p2 & 3) * 8);
    }
    // compute on current chunk
    short8 af = *(const short8*)&xs[cur][rt * 16 + r][hi * 8];
#pragma unroll
    for (int tt = 0; tt < 3; ++tt) {
      short8 bf = *(const short8*)&wsl[cur][(cg * 3 + tt) * 16 + r][hi * 8];
      acc[tt] = __builtin_amdgcn_mfma_f32_16x16x32_bf16(af, bf, acc[tt], 0, 0, 0);
    }
    // write next chunk to other buffer
    if (has_next) {
      int nb = cur ^ 1;
      unsigned int pk = (unsigned int)f2bf(xv[0]) | ((unsigned int)f2bf(xv[1]) << 16);
      *(unsigned int*)&xs[nb][xrow][xcol] = pk;
      *(short8*)&wsl[nb][p1 >> 2][(p1 & 3) * 8] = wva;
      if (tid < 256) *(short8*)&wsl[nb][p2 >> 2][(p2 & 3) * 8] = wvb;
    }
    __syncthreads();
  }

  // ---- epilogue: direct stores ----
  int lr = rt * 16 + hi * 4;        // local row base (+v)
#pragma unroll
  for (int tt = 0; tt < 3; ++tt) {
    int gt = cg * 3 + tt;
    if (gt < 8) {
      unsigned short* dst = (gt < 4) ? Qb : Kb;
      int col = (gt & 3) * 16 + r;
#pragma unroll
      for (int v = 0; v < 4; ++v)
        dst[(size_t)(sbase + lr + v) * 64 + col] = f2bf(acc[tt][v]);
    } else {
      int d = (gt - 8) * 16 + r;
      ushort4e pk;
#pragma unroll
      for (int v = 0; v < 4; ++v) pk[v] = f2bf(acc[tt][v]);
      int bidx = sbase >> 12;
      int so = (sbase & 4095) + lr;
      *(ushort4e*)(Vt + ((size_t)(bidx * 64 + d)) * 4096 + so) = pk;
    }
  }
}

// ---------------- Kernel 3: flash attention (FROZEN from R6) -----------------
// 1024 blocks x 256 threads (4 waves). bid -> (qidx heavy-first, b, hh).
// Wave part g = hh*4 + p handles KV pairs g, g+16, ... (pair = 64 rows).
// S^T = K.Q^T : C/D col = lane&31 = q-row ; kv = (reg&3)+8*(reg>>2)+4*(lane>>5)
__global__ __launch_bounds__(256, 2) void attn_kernel(
    const unsigned short* __restrict__ Qb, const unsigned short* __restrict__ Kb,
    const unsigned short* __restrict__ Vt, float* __restrict__ Opart,
    float* __restrict__ Mpart, float* __restrict__ Lpart) {
  int bid = blockIdx.x;             // 0..1023
  int q = 127 - (bid >> 3);         // heavy q first
  int b = (bid >> 2) & 1;
  int hh = bid & 3;
  int lane = threadIdx.x & 63;
  int p = threadIdx.x >> 6;         // 0..3
  int g = hh * 4 + p;               // KV part 0..15
  int ql = lane & 31;
  int h = lane >> 5;
  int sbase = q * 32;

  __shared__ float sm[4][32];
  __shared__ float sl[4][32];
  __shared__ alignas(16) float Op[4][32][68];

  const unsigned short* Qp = Qb + ((size_t)(b * 4096 + sbase + ql)) * 64 + h * 8;
  short8 qf0 = *(const short8*)(Qp);
  short8 qf1 = *(const short8*)(Qp + 16);
  short8 qf2 = *(const short8*)(Qp + 32);
  short8 qf3 = *(const short8*)(Qp + 48);

  f32x16 o0, o1;
#pragma unroll
  for (int i = 0; i < 16; ++i) { o0[i] = 0.f; o1[i] = 0.f; }
  float m = NEGINF, l = 0.f;

  int npairs = (q + 2) >> 1;
  const unsigned short* Kbb = Kb + (size_t)b * 4096 * 64;
  const unsigned short* Vbb = Vt + ((size_t)(b * 64 + ql)) * 4096 + h * 8;

  short8 k0a, k0b, k0c, k0d, k1a, k1b, k1c, k1d;
  {
    const unsigned short* Kp = Kbb + (size_t)(g * 64 + ql) * 64 + h * 8;
    k0a = *(const short8*)(Kp);
    k0b = *(const short8*)(Kp + 16);
    k0c = *(const short8*)(Kp + 32);
    k0d = *(const short8*)(Kp + 48);
    k1a = *(const short8*)(Kp + 2048);
    k1b = *(const short8*)(Kp + 2048 + 16);
    k1c = *(const short8*)(Kp + 2048 + 32);
    k1d = *(const short8*)(Kp + 2048 + 48);
  }

  for (int j = g; j < npairs; j += 16) {
    int kbase = j * 64;
    const unsigned short* Vp = Vbb + kbase;
    short8 vf0 = *(const short8*)(Vp);
    short8 vf1 = *(const short8*)(Vp + 16);
    short8 vf2 = *(const short8*)(Vp + 32);
    short8 vf3 = *(const short8*)(Vp + 48);
    short8 vg0 = *(const short8*)(Vp + 32 * 4096);
    short8 vg1 = *(const short8*)(Vp + 32 * 4096 + 16);
    short8 vg2 = *(const short8*)(Vp + 32 * 4096 + 32);
    short8 vg3 = *(const short8*)(Vp + 32 * 4096 + 48);

    f32x16 st0, st1;
#pragma unroll
    for (int i = 0; i < 16; ++i) { st0[i] = 0.f; st1[i] = 0.f; }
    __builtin_amdgcn_s_setprio(1);
    st0 = mfma32(k0a, qf0, st0);
    st0 = mfma32(k0b, qf1, st0);
    st0 = mfma32(k0c, qf2, st0);
    st0 = mfma32(k0d, qf3, st0);
    st1 = mfma32(k1a, qf0, st1);
    st1 = mfma32(k1b, qf1, st1);
    st1 = mfma32(k1c, qf2, st1);
    st1 = mfma32(k1d, qf3, st1);
    __builtin_amdgcn_s_setprio(0);

    if (j + 16 < npairs) {          // prefetch next pair's K
      const unsigned short* Kp = Kbb + (size_t)((j + 16) * 64 + ql) * 64 + h * 8;
      k0a = *(const short8*)(Kp);
      k0b = *(const short8*)(Kp + 16);
      k0c = *(const short8*)(Kp + 32);
      k0d = *(const short8*)(Kp + 48);
      k1a = *(const short8*)(Kp + 2048);
      k1b = *(const short8*)(Kp + 2048 + 16);
      k1c = *(const short8*)(Kp + 2048 + 32);
      k1d = *(const short8*)(Kp + 2048 + 48);
    }

    if (2 * j == q) {
#pragma unroll
      for (int rg = 0; rg < 16; ++rg) {
        int kvl = (rg & 3) + 8 * (rg >> 2) + 4 * h;
        if (kvl > ql) st0[rg] = NEGINF;
        st1[rg] = NEGINF;
      }
    } else if (2 * j + 1 == q) {
#pragma unroll
      for (int rg = 0; rg < 16; ++rg) {
        int kvl = (rg & 3) + 8 * (rg >> 2) + 4 * h;
        if (kvl > ql) st1[rg] = NEGINF;
      }
    }

    // ---- online softmax over 32 values (log2 domain) ----
    float mx[16];
#pragma unroll
    for (int i = 0; i < 16; ++i) mx[i] = fmaxf(st0[i], st1[i]);
#pragma unroll
    for (int s = 8; s >= 1; s >>= 1)
#pragma unroll
      for (int i = 0; i < s; ++i) mx[i] = fmaxf(mx[i], mx[i + s]);
    float tm = fmaxf(mx[0], __shfl_xor(mx[0], 32));
    float nm = fmaxf(m, tm);
    float alpha = exp2f(m - nm);
#pragma unroll
    for (int i = 0; i < 16; ++i) {
      st0[i] = exp2f(st0[i] - nm);
      st1[i] = exp2f(st1[i] - nm);
    }
    float sv[16];
#pragma unroll
    for (int i = 0; i < 16; ++i) sv[i] = st0[i] + st1[i];
#pragma unroll
    for (int s = 8; s >= 1; s >>= 1)
#pragma unroll
      for (int i = 0; i < s; ++i) sv[i] += sv[i + s];
    float sum = sv[0] + __shfl_xor(sv[0], 32);
    l = l * alpha + sum;
    m = nm;
#pragma unroll
    for (int i = 0; i < 16; ++i) { o0[i] *= alpha; o1[i] *= alpha; }

    // ---- pack P -> bf16 B-frags (shfl_xor exchange) ----
    unsigned int pw0[8], pw1[8], sw0[8], sw1[8];
#pragma unroll
    for (int t = 0; t < 8; ++t) {
      pw0[t] = (unsigned int)f2bf(st0[2 * t]) | ((unsigned int)f2bf(st0[2 * t + 1]) << 16);
      pw1[t] = (unsigned int)f2bf(st1[2 * t]) | ((unsigned int)f2bf(st1[2 * t + 1]) << 16);
    }
#pragma unroll
    for (int t = 0; t < 8; ++t) {
      sw0[t] = __shfl_xor(pw0[t], 32);
      sw1[t] = __shfl_xor(pw1[t], 32);
    }
    uint4e bw0 = {h ? sw0[2] : pw0[0], h ? sw0[3] : pw0[1], h ? pw0[2] : sw0[0], h ? pw0[3] : sw0[1]};
    uint4e bw1 = {h ? sw0[6] : pw0[4], h ? sw0[7] : pw0[5], h ? pw0[6] : sw0[4], h ? pw0[7] : sw0[5]};
    uint4e bw2 = {h ? sw1[2] : pw1[0], h ? sw1[3] : pw1[1], h ? pw1[2] : sw1[0], h ? pw1[3] : sw1[1]};
    uint4e bw3 = {h ? sw1[6] : pw1[4], h ? sw1[7] : pw1[5], h ? pw1[6] : sw1[4], h ? pw1[7] : sw1[5]};
    short8 pb0 = __builtin_bit_cast(short8, bw0);
    short8 pb1 = __builtin_bit_cast(short8, bw1);
    short8 pb2 = __builtin_bit_cast(short8, bw2);
    short8 pb3 = __builtin_bit_cast(short8, bw3);

    __builtin_amdgcn_s_setprio(1);
    o0 = mfma32(vf0, pb0, o0);
    o0 = mfma32(vf1, pb1, o0);
    o0 = mfma32(vf2, pb2, o0);
    o0 = mfma32(vf3, pb3, o0);
    o1 = mfma32(vg0, pb0, o1);
    o1 = mfma32(vg1, pb1, o1);
    o1 = mfma32(vg2, pb2, o1);
    o1 = mfma32(vg3, pb3, o1);
    __builtin_amdgcn_s_setprio(0);
  }

  // ---- LDS combine of this block's 4 waves -> global partial ----
  if (h == 0) sm[p][ql] = m;
  __syncthreads();
  float gm = sm[0][ql];
#pragma unroll
  for (int i = 1; i < 4; ++i) gm = fmaxf(gm, sm[i][ql]);
  float alpha = exp2f(m - gm);      // 0 for empty waves; 1 if all empty (l=0)
  if (h == 0) sl[p][ql] = alpha * l;
  float* Ob = &Op[p][ql][0];
#pragma unroll
  for (int u = 0; u < 4; ++u) {
    f32x4 w0 = {alpha * o0[4 * u], alpha * o0[4 * u + 1], alpha * o0[4 * u + 2], alpha * o0[4 * u + 3]};
    *(f32x4*)(Ob + u * 8 + h * 4) = w0;
    f32x4 w1 = {alpha * o1[4 * u], alpha * o1[4 * u + 1], alpha * o1[4 * u + 2], alpha * o1[4 * u + 3]};
    *(f32x4*)(Ob + 32 + u * 8 + h * 4) = w1;
  }
  __syncthreads();

  float* Od = Opart + (size_t)bid * 2048;
#pragma unroll
  for (int i = 0; i < 2; ++i) {
    int task = threadIdx.x + i * 256;
    int row = task >> 4;
    int c4 = (task & 15) * 4;
    f32x4 accv = *(const f32x4*)(&Op[0][row][c4]);
#pragma unroll
    for (int pp = 1; pp < 4; ++pp) accv += *(const f32x4*)(&Op[pp][row][c4]);
    *(f32x4*)(Od + row * 64 + c4) = accv;
  }
  if (threadIdx.x < 32) {
    int row = threadIdx.x;
    float gmv = fmaxf(fmaxf(sm[0][row], sm[1][row]), fmaxf(sm[2][row], sm[3][row]));
    Mpart[(size_t)bid * 32 + row] = gmv;
    Lpart[(size_t)bid * 32 + row] = sl[0][row] + sl[1][row] + sl[2][row] + sl[3][row];
  }
}

// ---------------- Kernel 4: combine 4 partials per q-tile --------------------
__global__ __launch_bounds__(256) void combine_kernel(
    const float* __restrict__ Opart, const float* __restrict__ Mpart,
    const float* __restrict__ Lpart, float* __restrict__ out) {
  int gid = blockIdx.x * 256 + threadIdx.x;   // 0..131071
  int c4 = (gid & 15) * 4;
  int row = gid >> 4;                         // b*4096 + s
  int r = row & 31;
  int qg = row >> 5;                          // b*128 + q
  int b = qg >> 7, q = qg & 127;
  int base = (127 - q) * 8 + b * 4;           // 4 partial blocks

  float mm[4];
  float gm = NEGINF;
#pragma unroll
  for (int i = 0; i < 4; ++i) {
    mm[i] = Mpart[(size_t)(base + i) * 32 + r];
    gm = fmaxf(gm, mm[i]);
  }
  float L = 0.f;
  f32x4 o = {0.f, 0.f, 0.f, 0.f};
#pragma unroll
  for (int i = 0; i < 4; ++i) {
    float e = exp2f(mm[i] - gm);
    L += e * Lpart[(size_t)(base + i) * 32 + r];
    f32x4 ov = *(const f32x4*)(Opart + (size_t)(base + i) * 2048 + r * 64 + c4);
    o += e * ov;
  }
  float invl = 1.0f / L;
  f32x4 res = {o[0] * invl, o[1] * invl, o[2] * invl, o[3] * invl};
  *(f32x4*)(out + (size_t)row * 64 + c4) = res;
}

// ---------------- launcher ---------------------------------------------------
extern "C" void kernel_launch(void* const* d_in, const int* in_sizes, int n_in,
                              void* d_out, int out_size, void* d_ws, size_t ws_size,
                              hipStream_t stream) {
  const float* x  = (const float*)d_in[0];
  const float* Wq = (const float*)d_in[1];
  const float* Wk = (const float*)d_in[2];
  const float* Wv = (const float*)d_in[3];
  float* out = (float*)d_out;

  if (ws_size < 12189696) return;  // tripwire (ws is ~268 MB per fill size)

  char* ws = (char*)d_ws;
  unsigned short* Wt = (unsigned short*)(ws + 0);          //   393216 B
  unsigned short* Qb = (unsigned short*)(ws + 393216);     //  1048576 B
  unsigned short* Kb = (unsigned short*)(ws + 1441792);    //  1048576 B
  unsigned short* Vt = (unsigned short*)(ws + 2490368);    //  1048576 B
  float* Opart = (float*)(ws + 3538944);                   //  8388608 B
  float* Mpart = (float*)(ws + 11927552);                  //   131072 B
  float* Lpart = (float*)(ws + 12058624);                  //   131072 B

  wprep_kernel<<<24, 256, 0, stream>>>(Wq, Wk, Wv, Wt);
  qkv_proj_kernel<<<256, 512, 0, stream>>>(x, Wt, Qb, Kb, Vt);
  attn_kernel<<<1024, 256, 0, stream>>>(Qb, Kb, Vt, Opart, Mpart, Lpart);
  combine_kernel<<<512, 256, 0, stream>>>(Opart, Mpart, Lpart, out);
}